// Round 4
// baseline (217.304 us; speedup 1.0000x reference)
//
#include <hip/hip_runtime.h>

#define TILE  256
#define CIN   32
#define COUT  64
#define LSIZE 16384
#define NBITS 14
#define MWPAD 68   // COUT+4: breaks the 32-way staging-write conflict (stride 68 % 32 = 4)

typedef float vfloat4 __attribute__((ext_vector_type(4)));

__global__ __launch_bounds__(256, 3)
void hamming_fused(const float* __restrict__ x,
                   const float* __restrict__ w_self,
                   const float* __restrict__ w_bits,
                   const float* __restrict__ mix_w,
                   const float* __restrict__ mix_b,
                   float* __restrict__ out)
{
    __shared__ float xs[CIN][TILE];      // 32 KiB (x tile, overwritten with y)
    __shared__ float mws[CIN][MWPAD];    // ~8.5 KiB, mws[c][o] = mix_w[o][c]

    const int tid = threadIdx.x;         // 0..255

    // XCD-aware remap: each XCD owns 4 whole batches -> x[b] slab L2-resident
    const int d    = blockIdx.x;
    const int xcd  = d & 7;
    const int j    = d >> 3;
    const int b    = xcd * 4 + (j >> 6);
    const int tile = j & 63;
    const int base = tile * TILE;
    const float* xb = x + (size_t)b * CIN * LSIZE;

    // ---- stage mix_w (transposed, padded rows) ----
    #pragma unroll
    for (int i = 0; i < 8; ++i) {
        int g = tid + i * 256;
        mws[g & 31][g >> 5] = mix_w[g];  // coalesced read; 4-way LDS write conflict only
    }

    // ---- stage x tile (coalesced float4) ----
    #pragma unroll
    for (int i = 0; i < 8; ++i) {
        int idx = tid + i * 256;
        int r  = idx >> 6;
        int c4 = (idx & 63) << 2;
        *(float4*)&xs[r][c4] =
            *(const float4*)(xb + (size_t)r * LSIZE + base + c4);
    }
    __syncthreads();

    const float ws = w_self[0];
    float wb[NBITS];
    #pragma unroll
    for (int k = 0; k < NBITS; ++k) wb[k] = w_bits[k];

    const int tx   = tid & 63;     // column quad
    const int grp  = tid >> 6;     // wave id: owns channels [8*grp, 8*grp+8)
    const int colb = tx << 2;
    const int c0   = grp * 8;
    const int gb   = base + colb;  // global column of quad start

    // ---- stage 1: each thread = 4 columns x 8 channels, all-b128 ----
    float4 yreg[8];
    #pragma unroll
    for (int cc = 0; cc < 8; ++cc) {
        const int c = c0 + cc;
        const float* xr = xb + (size_t)c * LSIZE;

        // cross-tile taps (bits 8..13): coalesced float4, L2/LLC-resident
        float4 g0 = *(const float4*)(xr + (gb ^ 256));
        float4 g1 = *(const float4*)(xr + (gb ^ 512));
        float4 g2 = *(const float4*)(xr + (gb ^ 1024));
        float4 g3 = *(const float4*)(xr + (gb ^ 2048));
        float4 g4 = *(const float4*)(xr + (gb ^ 4096));
        float4 g5 = *(const float4*)(xr + (gb ^ 8192));

        // self + bits 0,1: one b128, partners are component swaps
        float4 s = *(float4*)&xs[c][colb];
        float4 a;
        a.x = ws * s.x + wb[0] * s.y + wb[1] * s.z;
        a.y = ws * s.y + wb[0] * s.x + wb[1] * s.w;
        a.z = ws * s.z + wb[0] * s.w + wb[1] * s.x;
        a.w = ws * s.w + wb[0] * s.z + wb[1] * s.y;

        // bits 2..7: quad-aligned XOR -> one b128 each, component j aligns
        #pragma unroll
        for (int k = 2; k < 8; ++k) {
            float4 tp = *(float4*)&xs[c][colb ^ (1 << k)];
            a.x += wb[k] * tp.x;
            a.y += wb[k] * tp.y;
            a.z += wb[k] * tp.z;
            a.w += wb[k] * tp.w;
        }

        a.x += wb[8]*g0.x + wb[9]*g1.x + wb[10]*g2.x + wb[11]*g3.x + wb[12]*g4.x + wb[13]*g5.x;
        a.y += wb[8]*g0.y + wb[9]*g1.y + wb[10]*g2.y + wb[11]*g3.y + wb[12]*g4.y + wb[13]*g5.y;
        a.z += wb[8]*g0.z + wb[9]*g1.z + wb[10]*g2.z + wb[11]*g3.z + wb[12]*g4.z + wb[13]*g5.z;
        a.w += wb[8]*g0.w + wb[9]*g1.w + wb[10]*g2.w + wb[11]*g3.w + wb[12]*g4.w + wb[13]*g5.w;

        yreg[cc].x = a.x * (1.0f / 15.0f);
        yreg[cc].y = a.y * (1.0f / 15.0f);
        yreg[cc].z = a.z * (1.0f / 15.0f);
        yreg[cc].w = a.w * (1.0f / 15.0f);
    }

    // write y back in-place. No barrier needed before: each wave reads/writes
    // ONLY its own 8 rows of xs, and all its reads precede these writes.
    #pragma unroll
    for (int cc = 0; cc < 8; ++cc)
        *(float4*)&xs[c0 + cc][colb] = yreg[cc];
    __syncthreads();

    // ---- stage 2: channel mix, thread = 4 columns x 16 outputs ----
    const int o0 = grp * 16;

    float4 acc[16];
    #pragma unroll
    for (int jj = 0; jj < 16; ++jj) {
        float bias = mix_b[o0 + jj];
        acc[jj] = make_float4(bias, bias, bias, bias);
    }

    #pragma unroll 4
    for (int c = 0; c < CIN; ++c) {
        float4 yv = *(float4*)&xs[c][colb];
        #pragma unroll
        for (int j4 = 0; j4 < 4; ++j4) {
            float4 m = *(float4*)&mws[c][o0 + j4 * 4];   // wave-uniform broadcast
            acc[j4*4+0].x += m.x * yv.x; acc[j4*4+0].y += m.x * yv.y;
            acc[j4*4+0].z += m.x * yv.z; acc[j4*4+0].w += m.x * yv.w;
            acc[j4*4+1].x += m.y * yv.x; acc[j4*4+1].y += m.y * yv.y;
            acc[j4*4+1].z += m.y * yv.z; acc[j4*4+1].w += m.y * yv.w;
            acc[j4*4+2].x += m.z * yv.x; acc[j4*4+2].y += m.z * yv.y;
            acc[j4*4+2].z += m.z * yv.z; acc[j4*4+2].w += m.z * yv.w;
            acc[j4*4+3].x += m.w * yv.x; acc[j4*4+3].y += m.w * yv.y;
            acc[j4*4+3].z += m.w * yv.z; acc[j4*4+3].w += m.w * yv.w;
        }
    }

    // ---- store: coalesced float4, non-temporal (don't evict x from L2/LLC) ----
    float* ob = out + (size_t)b * COUT * LSIZE;
    #pragma unroll
    for (int jj = 0; jj < 16; ++jj) {
        vfloat4 v; v.x = acc[jj].x; v.y = acc[jj].y; v.z = acc[jj].z; v.w = acc[jj].w;
        vfloat4* p = (vfloat4*)(ob + (size_t)(o0 + jj) * LSIZE + base + colb);
        __builtin_nontemporal_store(v, p);
    }
}

extern "C" void kernel_launch(void* const* d_in, const int* in_sizes, int n_in,
                              void* d_out, int out_size, void* d_ws, size_t ws_size,
                              hipStream_t stream) {
    const float* x      = (const float*)d_in[0];
    const float* w_self = (const float*)d_in[1];
    const float* w_bits = (const float*)d_in[2];
    const float* mix_w  = (const float*)d_in[3];
    const float* mix_b  = (const float*)d_in[4];
    float* out = (float*)d_out;

    hamming_fused<<<dim3(2048), 256, 0, stream>>>(x, w_self, w_bits, mix_w, mix_b, out);
}